// Round 2
// baseline (578.253 us; speedup 1.0000x reference)
//
#include <hip/hip_runtime.h>
#include <hip/hip_bf16.h>

// Problem constants (from reference setup_inputs)
constexpr int MP = 10242;   // coarse vertices (output rows)
constexpr int B  = 16;      // batch
constexpr int M  = 40962;   // fine vertices
constexpr int F  = 128;     // features
constexpr int ST = 1024;                    // setup kernel threads (single block)
constexpr int ITEMS = (MP + ST - 1) / ST;   // 11 entries per thread in the scan

// ---------------------------------------------------------------------------
// Fused setup: LDS histogram -> in-place exclusive scan -> CSR scatter.
// One block; all counts/cursor state lives in LDS (45 KB), so no global
// memset and no multi-kernel pipeline.
__global__ __launch_bounds__(ST)
void setup_kernel(const int* __restrict__ rows,
                  const int* __restrict__ cols,
                  const float* __restrict__ vals,
                  int* __restrict__ offsets,   // [MP+1] global, for pool kernel
                  int* __restrict__ scol,      // [nnz]
                  float* __restrict__ sval,    // [nnz]
                  int nnz) {
    __shared__ int cnt[MP];    // histogram -> exclusive offsets -> scatter cursor
    __shared__ int wsum[ST];   // per-thread chunk sums for the block scan
    int t = threadIdx.x;

    // zero the histogram
    for (int i = t; i < MP; i += ST) cnt[i] = 0;
    __syncthreads();

    // histogram rows into LDS
    for (int k = t; k < nnz; k += ST) atomicAdd(&cnt[rows[k]], 1);
    __syncthreads();

    // blocked exclusive scan: thread t owns cnt[t*ITEMS .. t*ITEMS+ITEMS)
    int base = t * ITEMS;
    int local[ITEMS];
    int run = 0;
    for (int i = 0; i < ITEMS; ++i) {
        int idx = base + i;
        int c = (idx < MP) ? cnt[idx] : 0;
        local[i] = run;          // exclusive within chunk
        run += c;
    }
    wsum[t] = run;
    __syncthreads();
    // Hillis-Steele inclusive scan over the 1024 chunk sums
    for (int off = 1; off < ST; off <<= 1) {
        int v = (t >= off) ? wsum[t - off] : 0;
        __syncthreads();
        wsum[t] += v;
        __syncthreads();
    }
    int excl = wsum[t] - run;    // exclusive prefix of this chunk
    // write exclusive offsets back into cnt (own chunk only) and to global
    for (int i = 0; i < ITEMS; ++i) {
        int idx = base + i;
        if (idx < MP) {
            int o = excl + local[i];
            cnt[idx] = o;
            offsets[idx] = o;
        }
    }
    if (t == ST - 1) offsets[MP] = wsum[ST - 1];
    __syncthreads();

    // scatter (col,val) into CSR order; cnt now serves as the cursor
    for (int k = t; k < nnz; k += ST) {
        int p = rows[k];
        int pos = atomicAdd(&cnt[p], 1);
        scol[pos] = cols[k];
        sval[pos] = vals[k];
    }
}

// ---------------------------------------------------------------------------
// Pool: each wave handles one coarse vertex p for TWO batch slices.
// Half-wave (32 lanes) x float4 = full 512 B feature row, coalesced for both
// the x gather and the out store. Inner loop batches 4 nnz so the 4 x-gathers
// issue independently (breaks the serial load-latency chain).
__global__ __launch_bounds__(256)
void pool_kernel(const float4* __restrict__ x,
                 const int* __restrict__ offsets,
                 const int* __restrict__ scol,
                 const float* __restrict__ sval,
                 float4* __restrict__ out) {
    int w    = blockIdx.x * 4 + (threadIdx.x >> 6); // global wave id, [0, MP*8)
    int lane = threadIdx.x & 63;
    int p = w >> 3;                                 // coarse vertex
    int b = ((w & 7) << 1) | (lane >> 5);           // batch slice (2 per wave)
    int l = lane & 31;                              // float4 index within row

    int s = offsets[p];
    int e = offsets[p + 1];
    const float4* xb = x + (size_t)b * M * (F / 4);

    float4 acc; acc.x = acc.y = acc.z = acc.w = 0.f;
    int i = s;
    for (; i + 4 <= e; i += 4) {
        int   c0 = scol[i],     c1 = scol[i + 1], c2 = scol[i + 2], c3 = scol[i + 3];
        float v0 = sval[i],     v1 = sval[i + 1], v2 = sval[i + 2], v3 = sval[i + 3];
        float4 a0 = xb[(size_t)c0 * (F / 4) + l];
        float4 a1 = xb[(size_t)c1 * (F / 4) + l];
        float4 a2 = xb[(size_t)c2 * (F / 4) + l];
        float4 a3 = xb[(size_t)c3 * (F / 4) + l];
        acc.x = fmaf(v0, a0.x, fmaf(v1, a1.x, fmaf(v2, a2.x, fmaf(v3, a3.x, acc.x))));
        acc.y = fmaf(v0, a0.y, fmaf(v1, a1.y, fmaf(v2, a2.y, fmaf(v3, a3.y, acc.y))));
        acc.z = fmaf(v0, a0.z, fmaf(v1, a1.z, fmaf(v2, a2.z, fmaf(v3, a3.z, acc.z))));
        acc.w = fmaf(v0, a0.w, fmaf(v1, a1.w, fmaf(v2, a2.w, fmaf(v3, a3.w, acc.w))));
    }
    for (; i < e; ++i) {
        int c = scol[i];
        float v = sval[i];
        float4 a = xb[(size_t)c * (F / 4) + l];
        acc.x = fmaf(v, a.x, acc.x);
        acc.y = fmaf(v, a.y, acc.y);
        acc.z = fmaf(v, a.z, acc.z);
        acc.w = fmaf(v, a.w, acc.w);
    }
    out[((size_t)b * MP + p) * (F / 4) + l] = acc;
}

// ---------------------------------------------------------------------------
extern "C" void kernel_launch(void* const* d_in, const int* in_sizes, int n_in,
                              void* d_out, int out_size, void* d_ws, size_t ws_size,
                              hipStream_t stream) {
    const float* x    = (const float*)d_in[0];
    const int*   rows = (const int*)d_in[1];
    const int*   cols = (const int*)d_in[2];
    const float* vals = (const float*)d_in[3];
    float* out = (float*)d_out;
    const int nnz = in_sizes[1];

    // Workspace: offsets[MP+1] | scol[nnz] | sval[nnz]
    int*   offsets = (int*)d_ws;
    int*   scol    = offsets + (MP + 1);
    float* sval    = (float*)(scol + nnz);

    setup_kernel<<<1, ST, 0, stream>>>(rows, cols, vals, offsets, scol, sval, nnz);

    // MP*8 waves (p x 8 b-pairs), 4 waves per 256-thread block
    pool_kernel<<<MP * 2, 256, 0, stream>>>((const float4*)x, offsets, scol, sval,
                                            (float4*)out);
}

// Round 3
// 461.677 us; speedup vs baseline: 1.2525x; 1.2525x over previous
//
#include <hip/hip_runtime.h>
#include <hip/hip_bf16.h>

// Problem constants (from reference setup_inputs)
constexpr int MP  = 10242;  // coarse vertices (output rows)
constexpr int B   = 16;     // batch
constexpr int M   = 40962;  // fine vertices
constexpr int F   = 128;    // features
constexpr int CAP = 32;     // ELL capacity per row; counts ~Poisson(4), P(>32) ~ 1e-18

// ---------------------------------------------------------------------------
// Build ELL: one pass, grid-wide. counts[] doubles as the insertion cursor.
__global__ void build_ell_kernel(const int* __restrict__ rows,
                                 const int* __restrict__ cols,
                                 const float* __restrict__ vals,
                                 int* __restrict__ counts,   // [MP], pre-zeroed
                                 int* __restrict__ scol,     // [MP*CAP]
                                 float* __restrict__ sval,   // [MP*CAP]
                                 int nnz) {
    int k = blockIdx.x * blockDim.x + threadIdx.x;
    if (k < nnz) {
        int p = rows[k];
        int slot = atomicAdd(&counts[p], 1);
        if (slot < CAP) {                 // safety clamp; never triggers at Poisson(4)
            scol[p * CAP + slot] = cols[k];
            sval[p * CAP + slot] = vals[k];
        }
    }
}

// ---------------------------------------------------------------------------
// Pool: each wave handles one coarse vertex p for TWO batch slices.
// Half-wave (32 lanes) x float4 = full 512 B feature row, coalesced for both
// the x gather and the out store. 4-way unrolled gather keeps 8 x-row loads
// in flight per wave (breaks the serial load-latency chain).
__global__ __launch_bounds__(256)
void pool_kernel(const float4* __restrict__ x,
                 const int* __restrict__ counts,
                 const int* __restrict__ scol,
                 const float* __restrict__ sval,
                 float4* __restrict__ out) {
    int w    = blockIdx.x * 4 + (threadIdx.x >> 6); // global wave id, [0, MP*8)
    int lane = threadIdx.x & 63;
    int p = w >> 3;                                 // coarse vertex
    int b = ((w & 7) << 1) | (lane >> 5);           // batch slice (2 per wave)
    int l = lane & 31;                              // float4 index within row

    int n = counts[p];
    n = n < CAP ? n : CAP;
    const int*   pc = scol + p * CAP;
    const float* pv = sval + p * CAP;
    const float4* xb = x + (size_t)b * M * (F / 4);

    float4 acc; acc.x = acc.y = acc.z = acc.w = 0.f;
    int j = 0;
    for (; j + 4 <= n; j += 4) {
        int   c0 = pc[j],     c1 = pc[j + 1], c2 = pc[j + 2], c3 = pc[j + 3];
        float v0 = pv[j],     v1 = pv[j + 1], v2 = pv[j + 2], v3 = pv[j + 3];
        float4 a0 = xb[(size_t)c0 * (F / 4) + l];
        float4 a1 = xb[(size_t)c1 * (F / 4) + l];
        float4 a2 = xb[(size_t)c2 * (F / 4) + l];
        float4 a3 = xb[(size_t)c3 * (F / 4) + l];
        acc.x = fmaf(v0, a0.x, fmaf(v1, a1.x, fmaf(v2, a2.x, fmaf(v3, a3.x, acc.x))));
        acc.y = fmaf(v0, a0.y, fmaf(v1, a1.y, fmaf(v2, a2.y, fmaf(v3, a3.y, acc.y))));
        acc.z = fmaf(v0, a0.z, fmaf(v1, a1.z, fmaf(v2, a2.z, fmaf(v3, a3.z, acc.z))));
        acc.w = fmaf(v0, a0.w, fmaf(v1, a1.w, fmaf(v2, a2.w, fmaf(v3, a3.w, acc.w))));
    }
    for (; j < n; ++j) {
        int c = pc[j];
        float v = pv[j];
        float4 a = xb[(size_t)c * (F / 4) + l];
        acc.x = fmaf(v, a.x, acc.x);
        acc.y = fmaf(v, a.y, acc.y);
        acc.z = fmaf(v, a.z, acc.z);
        acc.w = fmaf(v, a.w, acc.w);
    }
    out[((size_t)b * MP + p) * (F / 4) + l] = acc;
}

// ---------------------------------------------------------------------------
extern "C" void kernel_launch(void* const* d_in, const int* in_sizes, int n_in,
                              void* d_out, int out_size, void* d_ws, size_t ws_size,
                              hipStream_t stream) {
    const float* x    = (const float*)d_in[0];
    const int*   rows = (const int*)d_in[1];
    const int*   cols = (const int*)d_in[2];
    const float* vals = (const float*)d_in[3];
    float* out = (float*)d_out;
    const int nnz = in_sizes[1];

    // Workspace: counts[MP] | scol[MP*CAP] | sval[MP*CAP]
    int*   counts = (int*)d_ws;
    int*   scol   = counts + MP;
    float* sval   = (float*)(scol + MP * CAP);

    hipMemsetAsync(counts, 0, MP * sizeof(int), stream);

    int nb = (nnz + 255) / 256;
    build_ell_kernel<<<nb, 256, 0, stream>>>(rows, cols, vals, counts, scol, sval, nnz);

    // MP*8 waves (p x 8 batch-pairs), 4 waves per 256-thread block
    pool_kernel<<<MP * 2, 256, 0, stream>>>((const float4*)x, counts, scol, sval,
                                            (float4*)out);
}